// Round 8
// baseline (272.145 us; speedup 1.0000x reference)
//
#include <hip/hip_runtime.h>
#include <hip/hip_cooperative_groups.h>
#include <math.h>

namespace cg = cooperative_groups;

// ---------------------------------------------------------------------------
// PreLossSampler (N=1024):
//   out = [reg_valid | labels | max_overlaps | gt_assignment]  (4096 float32)
//
// ONE cooperative kernel (256 blocks x 256 threads, 4 waves/CU co-resident),
// grid.sync() between stages:
//   P1: elementwise outs + circles + WAVE-PER-ELEMENT stable rank sort
//       (lane counts 16 keys, 6-shfl butterfly) -> order/sbox/circ_s.
//   P2: supA. Block owns 4 sorted rows (i = b + 256v). Per-wave circle scan
//       -> block LDS buffer (LDS atomicAdd; max 2816 pairs/block < 4096 cap,
//       no overflow path needed) -> dense multi-wave clip eval -> LDS
//       atomicOr suppression -> global sup (every word written).
//   P3: nms. Block 0 runs the validated single-wave greedy scan (all 256
//       threads participate in barriers; lanes >= 64 idle).
//   P4: outB. Block owns 4 pred rows; sampled+circle scan -> LDS buffer ->
//       dense IoU3D eval -> per-row packed (iou,1023-j) u64 LDS atomicMax ->
//       writes out[2], out[3] directly.
//
// Exactness: identical arithmetic to the absmax-0.0-validated round-6/7
// kernels (clip, circle reject, rank predicate, nms logic, max packing).
// Fallback: if hipLaunchCooperativeKernel errors, the same 4 phases run as
// standalone kernels (identical outputs).
// ---------------------------------------------------------------------------

#define NB 1024

typedef unsigned long long u64;

__device__ __forceinline__ bool pt_in_box(float px, float py,
        float bx, float by, float bdx, float bdy, float cs, float sn) {
    float dx = px - bx, dy = py - by;
    float lx = dx * cs + dy * sn;
    float ly = dy * cs - dx * sn;
    return (fabsf(lx) <= bdx * 0.5f + 1e-5f) && (fabsf(ly) <= bdy * 0.5f + 1e-5f);
}

__device__ __forceinline__ unsigned sortbits(float f) {
    unsigned u = __float_as_uint(f + 0.0f);
    return (u & 0x80000000u) ? ~u : (u | 0x80000000u);
}

// Rotated-rectangle intersection area; reference-exact op order; all arrays
// <= 96 B, statically indexed (register-resident). Validated absmax 0.0.
__device__ float rect_inter_area(
        float ax, float ay, float adx, float ady, float ar,
        float bx, float by, float bdx, float bdy, float br) {
    float dcx = ax - bx, dcy = ay - by;
    float ra = 0.5f * sqrtf(adx * adx + ady * ady);
    float rb = 0.5f * sqrtf(bdx * bdx + bdy * bdy);
    float lim = ra + rb + 1e-3f;
    if (dcx * dcx + dcy * dcy > lim * lim) return 0.0f;

    float csa = cosf(ar), sna = sinf(ar);
    float csb = cosf(br), snb = sinf(br);
    float cax[4], cay[4], cbx[4], cby[4];
    const float SX[4] = {0.5f, 0.5f, -0.5f, -0.5f};
    const float SY[4] = {0.5f, -0.5f, -0.5f, 0.5f};
#pragma unroll
    for (int i = 0; i < 4; ++i) {
        float lx = SX[i] * adx, ly = SY[i] * ady;
        cax[i] = lx * csa - ly * sna + ax;
        cay[i] = lx * sna + ly * csa + ay;
        float mx = SX[i] * bdx, my = SY[i] * bdy;
        cbx[i] = mx * csb - my * snb + bx;
        cby[i] = mx * snb + my * csb + by;
    }

    unsigned vmask = 0u;
    float sx = 0.0f, sy = 0.0f;
#pragma unroll
    for (int i = 0; i < 4; ++i) {
        bool v = pt_in_box(cax[i], cay[i], bx, by, bdx, bdy, csb, snb);
        vmask |= v ? (1u << i) : 0u;
        sx += v ? cax[i] : 0.0f;
        sy += v ? cay[i] : 0.0f;
    }
#pragma unroll
    for (int i = 0; i < 4; ++i) {
        bool v = pt_in_box(cbx[i], cby[i], ax, ay, adx, ady, csa, sna);
        vmask |= v ? (1u << (4 + i)) : 0u;
        sx += v ? cbx[i] : 0.0f;
        sy += v ? cby[i] : 0.0f;
    }
#pragma unroll
    for (int i = 0; i < 4; ++i) {
        float a0x = cax[i], a0y = cay[i];
        float d1x = cax[(i + 1) & 3] - a0x, d1y = cay[(i + 1) & 3] - a0y;
#pragma unroll
        for (int j = 0; j < 4; ++j) {
            int s = 8 + i * 4 + j;
            float b0x = cbx[j], b0y = cby[j];
            float d2x = cbx[(j + 1) & 3] - b0x, d2y = cby[(j + 1) & 3] - b0y;
            float r0x = b0x - a0x, r0y = b0y - a0y;
            float den = d1x * d2y - d1y * d2x;
            bool nz = fabsf(den) > 1e-8f;
            float sden = nz ? den : 1.0f;
            float t = (r0x * d2y - r0y * d2x) / sden;
            float u = (r0x * d1y - r0y * d1x) / sden;
            bool ok = nz && t >= 0.0f && t <= 1.0f && u >= 0.0f && u <= 1.0f;
            float ipx = a0x + t * d1x;
            float ipy = a0y + t * d1y;
            vmask |= ok ? (1u << s) : 0u;
            sx += ok ? ipx : 0.0f;
            sy += ok ? ipy : 0.0f;
        }
    }
    int kc = __popc(vmask);
    if (kc < 3) return 0.0f;
    float ctrx = sx / (float)kc, ctry = sy / (float)kc;

    float cx24[24], cy24[24];
    unsigned h[24];
#pragma unroll
    for (int i = 0; i < 4; ++i) {
        {
            bool v = (vmask >> i) & 1u;
            float cx = v ? cax[i] - ctrx : 0.0f;
            float cy = v ? cay[i] - ctry : 0.0f;
            cx24[i] = cx; cy24[i] = cy;
            h[i] = sortbits(v ? atan2f(cy, cx) : 1e9f);
        }
        {
            bool v = (vmask >> (4 + i)) & 1u;
            float cx = v ? cbx[i] - ctrx : 0.0f;
            float cy = v ? cby[i] - ctry : 0.0f;
            cx24[4 + i] = cx; cy24[4 + i] = cy;
            h[4 + i] = sortbits(v ? atan2f(cy, cx) : 1e9f);
        }
    }
#pragma unroll
    for (int i = 0; i < 4; ++i) {
        float a0x = cax[i], a0y = cay[i];
        float d1x = cax[(i + 1) & 3] - a0x, d1y = cay[(i + 1) & 3] - a0y;
#pragma unroll
        for (int j = 0; j < 4; ++j) {
            int s = 8 + i * 4 + j;
            float b0x = cbx[j], b0y = cby[j];
            float d2x = cbx[(j + 1) & 3] - b0x, d2y = cby[(j + 1) & 3] - b0y;
            float r0x = b0x - a0x, r0y = b0y - a0y;
            float den = d1x * d2y - d1y * d2x;
            bool nz = fabsf(den) > 1e-8f;
            float sden = nz ? den : 1.0f;
            float t = (r0x * d2y - r0y * d2x) / sden;
            bool v = (vmask >> s) & 1u;
            float ipx = a0x + t * d1x;
            float ipy = a0y + t * d1y;
            float cx = v ? ipx - ctrx : 0.0f;
            float cy = v ? ipy - ctry : 0.0f;
            cx24[s] = cx; cy24[s] = cy;
            h[s] = sortbits(v ? atan2f(cy, cx) : 1e9f);
        }
    }

    int rk[24];
#pragma unroll
    for (int s = 0; s < 24; ++s) rk[s] = 0;
#pragma unroll
    for (int s = 0; s < 24; ++s) {
#pragma unroll
        for (int t = s + 1; t < 24; ++t) {
            bool a = h[s] <= h[t];
            rk[t] += a ? 1 : 0;
            rk[s] += a ? 0 : 1;
        }
    }

    float acc = 0.0f;
    float fx = 0.0f, fy = 0.0f, lx2 = 0.0f, ly2 = 0.0f;
    float pxp = 0.0f, pyp = 0.0f;
#pragma unroll
    for (int p = 0; p < 24; ++p) {
        float X = 0.0f, Y = 0.0f;
#pragma unroll
        for (int s = 0; s < 24; ++s) {
            bool m = (rk[s] == p);
            X = m ? cx24[s] : X;
            Y = m ? cy24[s] : Y;
        }
        if (p == 0) {
            fx = X; fy = Y;
        } else {
            float cr = pxp * Y - pyp * X;
            acc += (p < kc) ? cr : 0.0f;
        }
        bool e = (p == kc - 1);
        lx2 = e ? X : lx2;
        ly2 = e ? Y : ly2;
        pxp = X; pyp = Y;
    }
    acc += lx2 * fy - ly2 * fx;
    return 0.5f * fabsf(acc);
}

// ---------------------------------------------------------------------------
// Phase device functions (shared by cooperative kernel and fallbacks).
// ---------------------------------------------------------------------------

// P1: wave (global id w) handles element e = w.
__device__ void phase_prep(int b, int tid,
        const float* __restrict__ labels, const float* __restrict__ cls,
        const float* __restrict__ gt, const float* __restrict__ pred,
        float* __restrict__ out, int* __restrict__ order,
        float* __restrict__ sbox, float4* __restrict__ circ_s,
        float4* __restrict__ circ_g, float4* __restrict__ circ_p) {
    int lane = tid & 63;
    int e = (b * 256 + tid) >> 6;  // global wave id = element, 0..1023
    float ke = labels[e];
    const float4* lab4 = (const float4*)labels;
    int cntr = 0;
#pragma unroll
    for (int kk = 0; kk < 4; ++kk) {
        float4 kv = lab4[lane * 4 + kk];
        int t0 = lane * 16 + kk * 4;
        cntr += ((kv.x > ke) || (kv.x == ke && (t0 + 0) < e)) ? 1 : 0;
        cntr += ((kv.y > ke) || (kv.y == ke && (t0 + 1) < e)) ? 1 : 0;
        cntr += ((kv.z > ke) || (kv.z == ke && (t0 + 2) < e)) ? 1 : 0;
        cntr += ((kv.w > ke) || (kv.w == ke && (t0 + 3) < e)) ? 1 : 0;
    }
#pragma unroll
    for (int off = 32; off > 0; off >>= 1) cntr += __shfl_xor(cntr, off, 64);
    int rank = cntr;  // stable argsort(-labels) position of e
    if (lane < 7) sbox[rank * 8 + lane] = gt[e * 8 + lane];
    if (lane == 7) sbox[rank * 8 + 7] = 0.0f;
    if (lane == 0) {
        order[rank] = e;
        float gdx = gt[e * 8 + 3], gdy = gt[e * 8 + 4];
        float4 cgc = make_float4(gt[e * 8 + 0], gt[e * 8 + 1],
                                 0.5f * sqrtf(gdx * gdx + gdy * gdy), 0.0f);
        circ_s[rank] = cgc;
        circ_g[e] = cgc;
        float pdx = pred[e * 7 + 3], pdy = pred[e * 7 + 4];
        circ_p[e] = make_float4(pred[e * 7 + 0], pred[e * 7 + 1],
                                0.5f * sqrtf(pdx * pdx + pdy * pdy), 0.0f);
        float sig = 1.0f / (1.0f + expf(-cls[e]));
        out[e] = (sig > 0.55f && ke > 0.55f) ? 1.0f : 0.0f;
        out[NB + e] = ke;
    }
}

// P2: block b owns sorted rows i = b + 256v, v = wave index.
__device__ void phase_supA(int b, int tid,
        const float* __restrict__ sbox, const float4* __restrict__ circ_s,
        u64* __restrict__ sup,
        unsigned* ring, unsigned* cnt_s, unsigned* sup32) {
    int lane = tid & 63;
    int wv = tid >> 6;
    if (tid == 0) *cnt_s = 0u;
    for (int t = tid; t < 128; t += 256) sup32[t] = 0u;
    __syncthreads();
    {
        int i = b + (wv << 8);
        float4 A = circ_s[i];
        int j0 = ((i + 1) >> 6) << 6;
        for (int jb = j0; jb < 1024; jb += 64) {
            int j = jb + lane;
            bool q = j > i;
            if (q) {
                float4 B = circ_s[j];
                float dx = A.x - B.x, dy = A.y - B.y;
                float lim = A.z + B.z + 1e-3f;
                q = (dx * dx + dy * dy) <= lim * lim;
            }
            if (q) {
                unsigned pos = atomicAdd(cnt_s, 1u);
                ring[pos] = (unsigned)((i << 10) | j);  // max 2816 < 4096
            }
        }
    }
    __syncthreads();
    {
        unsigned n = *cnt_s;
        for (unsigned t = tid; t < n; t += 256) {
            unsigned p = ring[t];
            int i = (p >> 10) & 1023, j = p & 1023;
            const float* A = &sbox[i * 8];
            const float* B = &sbox[j * 8];
            float inter = rect_inter_area(A[0], A[1], A[3], A[4], A[6],
                                          B[0], B[1], B[3], B[4], B[6]);
            float iou = inter / fmaxf(A[3] * A[4] + B[3] * B[4] - inter, 1e-8f);
            if (iou > 0.1f) {
                int r = (i - b) >> 8;
                atomicOr(&sup32[r * 32 + (j >> 5)], 1u << (j & 31));
            }
        }
    }
    __syncthreads();
    for (int t = tid; t < 64; t += 256) {
        int r = t >> 4, w = t & 15;
        int i = b + (r << 8);
        sup[i * 16 + w] = (u64)sup32[r * 32 + 2 * w] |
                          ((u64)sup32[r * 32 + 2 * w + 1] << 32);
    }
}

// P3: single-wave greedy NMS (validated); all threads of the block hit the
// barriers, lanes >= 64 idle.
__device__ void phase_nms(int tid,
        const u64* __restrict__ sup, const int* __restrict__ order,
        int* __restrict__ sampled, u64* bc) {
    int lane = tid & 63;
    u64 kw[16], acc[16], row[16];
    if (tid < 64) {
#pragma unroll
        for (int t = 0; t < 16; ++t) acc[t] = 0ULL;
#pragma unroll
        for (int t = 0; t < 16; ++t) row[t] = sup[(size_t)lane * 16 + t];
    }
#pragma unroll
    for (int W = 0; W < 16; ++W) {
        u64 kwW = 0ULL;
        if (tid < 64) {
            u64 v = acc[W];
#pragma unroll
            for (int off = 32; off > 0; off >>= 1) v |= __shfl_xor(v, off, 64);
            kwW = ~v;
            bc[lane] = row[W];
        }
        __syncthreads();
        if (tid < 64) {
            u64 rowN[16];
#pragma unroll
            for (int t = 0; t < 16; ++t) rowN[t] = 0ULL;
            if (W < 15) {
#pragma unroll
                for (int t = 0; t < 16; ++t)
                    if (t >= W + 1)
                        rowN[t] = sup[(size_t)((W + 1) * 64 + lane) * 16 + t];
            }
#pragma unroll
            for (int bb = 0; bb < 64; ++bb) {
                bool kb = (kwW >> bb) & 1ULL;
                kwW &= kb ? ~bc[bb] : ~0ULL;
            }
            kw[W] = kwW;
            bool me = (kwW >> lane) & 1ULL;
#pragma unroll
            for (int t = W + 1; t < 16; ++t) acc[t] |= me ? row[t] : 0ULL;
#pragma unroll
            for (int t = 0; t < 16; ++t) row[t] = rowN[t];
        }
        __syncthreads();
    }
    if (tid < 64) {
#pragma unroll
        for (int t = 0; t < 16; ++t) {
            int idx = t * 64 + lane;
            sampled[order[idx]] = (int)((kw[t] >> lane) & 1ULL);
        }
    }
}

// P4: block b owns pred rows i = b + 256v; writes out[2],out[3].
__device__ void phase_outB(int b, int tid,
        const float* __restrict__ pred, const float* __restrict__ gt,
        const int* __restrict__ sampled, const float4* __restrict__ circ_p,
        const float4* __restrict__ circ_g, float* __restrict__ out,
        unsigned* ring, unsigned* cnt_s, u64* rm) {
    int lane = tid & 63;
    int wv = tid >> 6;
    if (tid == 0) *cnt_s = 0u;
    if (tid < 4) rm[tid] = 1023ULL;  // pack(iou=0.0f, j=0)
    __syncthreads();
    {
        int i = b + (wv << 8);
        float4 A = circ_p[i];
        for (int jb = 0; jb < 1024; jb += 64) {
            int j = jb + lane;
            bool q = sampled[j] != 0;
            if (q) {
                float4 B = circ_g[j];
                float dx = A.x - B.x, dy = A.y - B.y;
                float lim = A.z + B.z + 1e-3f;
                q = (dx * dx + dy * dy) <= lim * lim;
            }
            if (q) {
                unsigned pos = atomicAdd(cnt_s, 1u);
                ring[pos] = (unsigned)((i << 10) | j);  // max 4096 = cap
            }
        }
    }
    __syncthreads();
    {
        unsigned n = *cnt_s;
        for (unsigned t = tid; t < n; t += 256) {
            unsigned p = ring[t];
            int i = (p >> 10) & 1023, j = p & 1023;
            float Ax = pred[i * 7 + 0], Ay = pred[i * 7 + 1], Az = pred[i * 7 + 2];
            float Adx = pred[i * 7 + 3], Ady = pred[i * 7 + 4], Adz = pred[i * 7 + 5];
            float Ar = pred[i * 7 + 6];
            float Bx = gt[j * 8 + 0], By = gt[j * 8 + 1], Bz = gt[j * 8 + 2];
            float Bdx = gt[j * 8 + 3], Bdy = gt[j * 8 + 4], Bdz = gt[j * 8 + 5];
            float Br = gt[j * 8 + 6];
            float inter = rect_inter_area(Ax, Ay, Adx, Ady, Ar,
                                          Bx, By, Bdx, Bdy, Br);
            float amax = Az + Adz * 0.5f, amin = Az - Adz * 0.5f;
            float bmax = Bz + Bdz * 0.5f, bmin = Bz - Bdz * 0.5f;
            float oh = fmaxf(fminf(amax, bmax) - fmaxf(amin, bmin), 0.0f);
            float inter3d = inter * oh;
            float va = Adx * Ady * Adz, vb = Bdx * Bdy * Bdz;
            float iou = inter3d / fmaxf(va + vb - inter3d, 1e-8f);
            u64 pk = (((u64)__float_as_uint(iou)) << 32) | (u64)(1023 - j);
            int r = (i - b) >> 8;
            atomicMax(&rm[r], pk);
        }
    }
    __syncthreads();
    if (tid < 4) {
        int i = b + (tid << 8);
        u64 v = rm[tid];
        float fv = __uint_as_float((unsigned)(v >> 32));
        int j = 1023 - (int)(v & 0xFFFFFFFFULL);
        float mo = (fv > 0.75f) ? 1.0f : ((fv < 0.25f) ? 0.0f : fv);
        out[2 * NB + i] = mo;
        out[3 * NB + i] = (float)j;
    }
}

// ---------------------------------------------------------------------------
// The cooperative kernel: all 4 phases, grid.sync() between.
// ---------------------------------------------------------------------------
__global__ __launch_bounds__(256) void fused_all_kernel(
        const float* __restrict__ labels, const float* __restrict__ pred,
        const float* __restrict__ gt, const float* __restrict__ cls,
        float* __restrict__ out, int* __restrict__ order,
        float* __restrict__ sbox, int* __restrict__ sampled,
        u64* __restrict__ sup, float4* __restrict__ circ_s,
        float4* __restrict__ circ_g, float4* __restrict__ circ_p) {
    __shared__ unsigned ring[4096];
    __shared__ unsigned cnt_s;
    __shared__ unsigned sup32[128];
    __shared__ u64 rm[4];
    __shared__ u64 bc[64];

    cg::grid_group grid = cg::this_grid();
    int tid = threadIdx.x;
    int b = blockIdx.x;

    phase_prep(b, tid, labels, cls, gt, pred, out, order, sbox,
               circ_s, circ_g, circ_p);
    grid.sync();
    phase_supA(b, tid, sbox, circ_s, sup, ring, &cnt_s, sup32);
    grid.sync();
    if (b == 0) phase_nms(tid, sup, order, sampled, bc);
    grid.sync();
    phase_outB(b, tid, pred, gt, sampled, circ_p, circ_g, out,
               ring, &cnt_s, rm);
}

// ---------------------------------------------------------------------------
// Fallback standalone kernels (identical outputs; used only if the
// cooperative launch is rejected, e.g. capture-unsupported).
// ---------------------------------------------------------------------------
__global__ __launch_bounds__(256) void prep_sa_kernel(
        const float* __restrict__ labels, const float* __restrict__ pred,
        const float* __restrict__ gt, const float* __restrict__ cls,
        float* __restrict__ out, int* __restrict__ order,
        float* __restrict__ sbox, float4* __restrict__ circ_s,
        float4* __restrict__ circ_g, float4* __restrict__ circ_p) {
    phase_prep(blockIdx.x, threadIdx.x, labels, cls, gt, pred, out, order,
               sbox, circ_s, circ_g, circ_p);
}

__global__ __launch_bounds__(256) void supA_sa_kernel(
        const float* __restrict__ sbox, const float4* __restrict__ circ_s,
        u64* __restrict__ sup) {
    __shared__ unsigned ring[4096];
    __shared__ unsigned cnt_s;
    __shared__ unsigned sup32[128];
    phase_supA(blockIdx.x, threadIdx.x, sbox, circ_s, sup, ring, &cnt_s, sup32);
}

__global__ __launch_bounds__(256) void nms_sa_kernel(
        const u64* __restrict__ sup, const int* __restrict__ order,
        int* __restrict__ sampled) {
    __shared__ u64 bc[64];
    phase_nms(threadIdx.x, sup, order, sampled, bc);
}

__global__ __launch_bounds__(256) void outB_sa_kernel(
        const float* __restrict__ pred, const float* __restrict__ gt,
        const int* __restrict__ sampled, const float4* __restrict__ circ_p,
        const float4* __restrict__ circ_g, float* __restrict__ out) {
    __shared__ unsigned ring[4096];
    __shared__ unsigned cnt_s;
    __shared__ u64 rm[4];
    phase_outB(blockIdx.x, threadIdx.x, pred, gt, sampled, circ_p, circ_g,
               out, ring, &cnt_s, rm);
}

// ---------------------------------------------------------------------------
// Workspace layout:
//   [0,       4096)    int   order[1024]
//   [4096,    36864)   float sbox[1024*8]
//   [36864,   40960)   int   sampled[1024]
//   [40960,   172032)  u64   sup[1024*16]
//   [172032,  188416)  float4 circ_s[1024]
//   [188416,  204800)  float4 circ_g[1024]
//   [204800,  221184)  float4 circ_p[1024]
// ---------------------------------------------------------------------------
extern "C" void kernel_launch(void* const* d_in, const int* in_sizes, int n_in,
                              void* d_out, int out_size, void* d_ws, size_t ws_size,
                              hipStream_t stream) {
    const float* labels = (const float*)d_in[0];
    const float* pred   = (const float*)d_in[1];
    const float* gt     = (const float*)d_in[2];
    const float* cls    = (const float*)d_in[3];
    float* out = (float*)d_out;

    char* ws = (char*)d_ws;
    int* order     = (int*)ws;
    float* sbox    = (float*)(ws + 4096);
    int* sampled   = (int*)(ws + 36864);
    u64* sup       = (u64*)(ws + 40960);
    float4* circ_s = (float4*)(ws + 172032);
    float4* circ_g = (float4*)(ws + 188416);
    float4* circ_p = (float4*)(ws + 204800);

    void* args[] = {
        (void*)&labels, (void*)&pred, (void*)&gt, (void*)&cls,
        (void*)&out, (void*)&order, (void*)&sbox, (void*)&sampled,
        (void*)&sup, (void*)&circ_s, (void*)&circ_g, (void*)&circ_p,
    };
    hipError_t err = hipLaunchCooperativeKernel(
        (const void*)fused_all_kernel, dim3(256), dim3(256), args, 0, stream);
    if (err != hipSuccess) {
        // Deterministic fallback: same phases as standalone kernels.
        prep_sa_kernel<<<256, 256, 0, stream>>>(labels, pred, gt, cls, out,
                                                order, sbox, circ_s, circ_g,
                                                circ_p);
        supA_sa_kernel<<<256, 256, 0, stream>>>(sbox, circ_s, sup);
        nms_sa_kernel<<<1, 256, 0, stream>>>(sup, order, sampled);
        outB_sa_kernel<<<256, 256, 0, stream>>>(pred, gt, sampled, circ_p,
                                                circ_g, out);
    }
}

// Round 9
// 156.550 us; speedup vs baseline: 1.7384x; 1.7384x over previous
//
#include <hip/hip_runtime.h>
#include <math.h>

// ---------------------------------------------------------------------------
// PreLossSampler (N=1024):
//   out = [reg_valid | labels | max_overlaps | gt_assignment]  (4096 float32)
//
// 4 standalone high-occupancy kernels (cooperative grid.sync measured at
// ~45 us/sync on gfx950 in round 8 — fusion is strictly worse than kernel
// boundaries here):
//   prep_sa : 256x256, wave-per-element stable rank sort (lane counts 16
//             keys, 6-shfl butterfly) + elementwise outs + circles.
//   supA_sa : 256x256, block owns 4 sorted rows (i = b + 256v). Circle scan
//             -> LDS pair buffer (worst case 2556 <= 4096, overflow-free) ->
//             dense clip eval -> LDS atomicOr -> global sup (all words).
//   nms_sa  : validated single-wave greedy NMS (serial floor ~25-30 us).
//   outB_sa : 256x256, block owns 4 pred rows; sampled+circle scan -> LDS
//             buffer (worst case 4096 = cap) -> dense IoU3D eval -> per-row
//             packed (iou,1023-j) u64 LDS atomicMax -> out[2], out[3].
//
// Exactness: identical arithmetic to the absmax-0.0-validated rounds 6-8
// (clip, circle reject, rank predicate, nms logic, max packing). LDS buffer
// order is nondeterministic but consumed only by order-independent
// atomicOr / atomicMax with exact (value, first-index) tie-break packing.
// ---------------------------------------------------------------------------

#define NB 1024

typedef unsigned long long u64;

__device__ __forceinline__ bool pt_in_box(float px, float py,
        float bx, float by, float bdx, float bdy, float cs, float sn) {
    float dx = px - bx, dy = py - by;
    float lx = dx * cs + dy * sn;
    float ly = dy * cs - dx * sn;
    return (fabsf(lx) <= bdx * 0.5f + 1e-5f) && (fabsf(ly) <= bdy * 0.5f + 1e-5f);
}

__device__ __forceinline__ unsigned sortbits(float f) {
    unsigned u = __float_as_uint(f + 0.0f);
    return (u & 0x80000000u) ? ~u : (u | 0x80000000u);
}

// Rotated-rectangle intersection area; reference-exact op order; all arrays
// <= 96 B, statically indexed (register-resident, zero scratch).
// Validated absmax 0.0.
__device__ float rect_inter_area(
        float ax, float ay, float adx, float ady, float ar,
        float bx, float by, float bdx, float bdy, float br) {
    float dcx = ax - bx, dcy = ay - by;
    float ra = 0.5f * sqrtf(adx * adx + ady * ady);
    float rb = 0.5f * sqrtf(bdx * bdx + bdy * bdy);
    float lim = ra + rb + 1e-3f;
    if (dcx * dcx + dcy * dcy > lim * lim) return 0.0f;

    float csa = cosf(ar), sna = sinf(ar);
    float csb = cosf(br), snb = sinf(br);
    float cax[4], cay[4], cbx[4], cby[4];
    const float SX[4] = {0.5f, 0.5f, -0.5f, -0.5f};
    const float SY[4] = {0.5f, -0.5f, -0.5f, 0.5f};
#pragma unroll
    for (int i = 0; i < 4; ++i) {
        float lx = SX[i] * adx, ly = SY[i] * ady;
        cax[i] = lx * csa - ly * sna + ax;
        cay[i] = lx * sna + ly * csa + ay;
        float mx = SX[i] * bdx, my = SY[i] * bdy;
        cbx[i] = mx * csb - my * snb + bx;
        cby[i] = mx * snb + my * csb + by;
    }

    unsigned vmask = 0u;
    float sx = 0.0f, sy = 0.0f;
#pragma unroll
    for (int i = 0; i < 4; ++i) {
        bool v = pt_in_box(cax[i], cay[i], bx, by, bdx, bdy, csb, snb);
        vmask |= v ? (1u << i) : 0u;
        sx += v ? cax[i] : 0.0f;
        sy += v ? cay[i] : 0.0f;
    }
#pragma unroll
    for (int i = 0; i < 4; ++i) {
        bool v = pt_in_box(cbx[i], cby[i], ax, ay, adx, ady, csa, sna);
        vmask |= v ? (1u << (4 + i)) : 0u;
        sx += v ? cbx[i] : 0.0f;
        sy += v ? cby[i] : 0.0f;
    }
#pragma unroll
    for (int i = 0; i < 4; ++i) {
        float a0x = cax[i], a0y = cay[i];
        float d1x = cax[(i + 1) & 3] - a0x, d1y = cay[(i + 1) & 3] - a0y;
#pragma unroll
        for (int j = 0; j < 4; ++j) {
            int s = 8 + i * 4 + j;
            float b0x = cbx[j], b0y = cby[j];
            float d2x = cbx[(j + 1) & 3] - b0x, d2y = cby[(j + 1) & 3] - b0y;
            float r0x = b0x - a0x, r0y = b0y - a0y;
            float den = d1x * d2y - d1y * d2x;
            bool nz = fabsf(den) > 1e-8f;
            float sden = nz ? den : 1.0f;
            float t = (r0x * d2y - r0y * d2x) / sden;
            float u = (r0x * d1y - r0y * d1x) / sden;
            bool ok = nz && t >= 0.0f && t <= 1.0f && u >= 0.0f && u <= 1.0f;
            float ipx = a0x + t * d1x;
            float ipy = a0y + t * d1y;
            vmask |= ok ? (1u << s) : 0u;
            sx += ok ? ipx : 0.0f;
            sy += ok ? ipy : 0.0f;
        }
    }
    int kc = __popc(vmask);
    if (kc < 3) return 0.0f;
    float ctrx = sx / (float)kc, ctry = sy / (float)kc;

    float cx24[24], cy24[24];
    unsigned h[24];
#pragma unroll
    for (int i = 0; i < 4; ++i) {
        {
            bool v = (vmask >> i) & 1u;
            float cx = v ? cax[i] - ctrx : 0.0f;
            float cy = v ? cay[i] - ctry : 0.0f;
            cx24[i] = cx; cy24[i] = cy;
            h[i] = sortbits(v ? atan2f(cy, cx) : 1e9f);
        }
        {
            bool v = (vmask >> (4 + i)) & 1u;
            float cx = v ? cbx[i] - ctrx : 0.0f;
            float cy = v ? cby[i] - ctry : 0.0f;
            cx24[4 + i] = cx; cy24[4 + i] = cy;
            h[4 + i] = sortbits(v ? atan2f(cy, cx) : 1e9f);
        }
    }
#pragma unroll
    for (int i = 0; i < 4; ++i) {
        float a0x = cax[i], a0y = cay[i];
        float d1x = cax[(i + 1) & 3] - a0x, d1y = cay[(i + 1) & 3] - a0y;
#pragma unroll
        for (int j = 0; j < 4; ++j) {
            int s = 8 + i * 4 + j;
            float b0x = cbx[j], b0y = cby[j];
            float d2x = cbx[(j + 1) & 3] - b0x, d2y = cby[(j + 1) & 3] - b0y;
            float r0x = b0x - a0x, r0y = b0y - a0y;
            float den = d1x * d2y - d1y * d2x;
            bool nz = fabsf(den) > 1e-8f;
            float sden = nz ? den : 1.0f;
            float t = (r0x * d2y - r0y * d2x) / sden;
            bool v = (vmask >> s) & 1u;
            float ipx = a0x + t * d1x;
            float ipy = a0y + t * d1y;
            float cx = v ? ipx - ctrx : 0.0f;
            float cy = v ? ipy - ctry : 0.0f;
            cx24[s] = cx; cy24[s] = cy;
            h[s] = sortbits(v ? atan2f(cy, cx) : 1e9f);
        }
    }

    int rk[24];
#pragma unroll
    for (int s = 0; s < 24; ++s) rk[s] = 0;
#pragma unroll
    for (int s = 0; s < 24; ++s) {
#pragma unroll
        for (int t = s + 1; t < 24; ++t) {
            bool a = h[s] <= h[t];
            rk[t] += a ? 1 : 0;
            rk[s] += a ? 0 : 1;
        }
    }

    float acc = 0.0f;
    float fx = 0.0f, fy = 0.0f, lx2 = 0.0f, ly2 = 0.0f;
    float pxp = 0.0f, pyp = 0.0f;
#pragma unroll
    for (int p = 0; p < 24; ++p) {
        float X = 0.0f, Y = 0.0f;
#pragma unroll
        for (int s = 0; s < 24; ++s) {
            bool m = (rk[s] == p);
            X = m ? cx24[s] : X;
            Y = m ? cy24[s] : Y;
        }
        if (p == 0) {
            fx = X; fy = Y;
        } else {
            float cr = pxp * Y - pyp * X;
            acc += (p < kc) ? cr : 0.0f;
        }
        bool e = (p == kc - 1);
        lx2 = e ? X : lx2;
        ly2 = e ? Y : ly2;
        pxp = X; pyp = Y;
    }
    acc += lx2 * fy - ly2 * fx;
    return 0.5f * fabsf(acc);
}

// ---------------------------------------------------------------------------
// prep_sa: 256x256. Wave (global id) handles element e; lane counts 16 keys;
// butterfly sum -> stable rank. Elementwise outs + circles + scatter.
// ---------------------------------------------------------------------------
__global__ __launch_bounds__(256) void prep_sa_kernel(
        const float* __restrict__ labels, const float* __restrict__ pred,
        const float* __restrict__ gt, const float* __restrict__ cls,
        float* __restrict__ out, int* __restrict__ order,
        float* __restrict__ sbox, float4* __restrict__ circ_s,
        float4* __restrict__ circ_g, float4* __restrict__ circ_p) {
    int tid = threadIdx.x;
    int lane = tid & 63;
    int e = ((int)blockIdx.x * 256 + tid) >> 6;  // global wave id = element
    float ke = labels[e];
    const float4* lab4 = (const float4*)labels;
    int cntr = 0;
#pragma unroll
    for (int kk = 0; kk < 4; ++kk) {
        float4 kv = lab4[lane * 4 + kk];
        int t0 = lane * 16 + kk * 4;
        cntr += ((kv.x > ke) || (kv.x == ke && (t0 + 0) < e)) ? 1 : 0;
        cntr += ((kv.y > ke) || (kv.y == ke && (t0 + 1) < e)) ? 1 : 0;
        cntr += ((kv.z > ke) || (kv.z == ke && (t0 + 2) < e)) ? 1 : 0;
        cntr += ((kv.w > ke) || (kv.w == ke && (t0 + 3) < e)) ? 1 : 0;
    }
#pragma unroll
    for (int off = 32; off > 0; off >>= 1) cntr += __shfl_xor(cntr, off, 64);
    int rank = cntr;  // stable argsort(-labels) position of e
    if (lane < 7) sbox[rank * 8 + lane] = gt[e * 8 + lane];
    if (lane == 7) sbox[rank * 8 + 7] = 0.0f;
    if (lane == 0) {
        order[rank] = e;
        float gdx = gt[e * 8 + 3], gdy = gt[e * 8 + 4];
        float4 cgc = make_float4(gt[e * 8 + 0], gt[e * 8 + 1],
                                 0.5f * sqrtf(gdx * gdx + gdy * gdy), 0.0f);
        circ_s[rank] = cgc;
        circ_g[e] = cgc;
        float pdx = pred[e * 7 + 3], pdy = pred[e * 7 + 4];
        circ_p[e] = make_float4(pred[e * 7 + 0], pred[e * 7 + 1],
                                0.5f * sqrtf(pdx * pdx + pdy * pdy), 0.0f);
        float sig = 1.0f / (1.0f + expf(-cls[e]));
        out[e] = (sig > 0.55f && ke > 0.55f) ? 1.0f : 0.0f;
        out[NB + e] = ke;
    }
}

// ---------------------------------------------------------------------------
// supA_sa: block b owns sorted rows i = b + 256v (v = wave). Circle scan ->
// LDS buffer (worst case 2556 <= 4096) -> dense clip eval -> LDS atomicOr ->
// global sup (all 16 words of all 4 rows written).
// ---------------------------------------------------------------------------
__global__ __launch_bounds__(256) void supA_sa_kernel(
        const float* __restrict__ sbox, const float4* __restrict__ circ_s,
        u64* __restrict__ sup) {
    __shared__ unsigned ring[4096];
    __shared__ unsigned cnt_s;
    __shared__ unsigned sup32[128];
    int tid = threadIdx.x;
    int b = blockIdx.x;
    int lane = tid & 63;
    int wv = tid >> 6;
    if (tid == 0) cnt_s = 0u;
    for (int t = tid; t < 128; t += 256) sup32[t] = 0u;
    __syncthreads();
    {
        int i = b + (wv << 8);
        float4 A = circ_s[i];
        int j0 = ((i + 1) >> 6) << 6;
        for (int jb = j0; jb < 1024; jb += 64) {
            int j = jb + lane;
            bool q = j > i;
            if (q) {
                float4 B = circ_s[j];
                float dx = A.x - B.x, dy = A.y - B.y;
                float lim = A.z + B.z + 1e-3f;
                q = (dx * dx + dy * dy) <= lim * lim;
            }
            if (q) {
                unsigned pos = atomicAdd(&cnt_s, 1u);
                ring[pos] = (unsigned)((i << 10) | j);
            }
        }
    }
    __syncthreads();
    {
        unsigned n = cnt_s;
        for (unsigned t = tid; t < n; t += 256) {
            unsigned p = ring[t];
            int i = (p >> 10) & 1023, j = p & 1023;
            const float* A = &sbox[i * 8];
            const float* B = &sbox[j * 8];
            float inter = rect_inter_area(A[0], A[1], A[3], A[4], A[6],
                                          B[0], B[1], B[3], B[4], B[6]);
            float iou = inter / fmaxf(A[3] * A[4] + B[3] * B[4] - inter, 1e-8f);
            if (iou > 0.1f) {
                int r = (i - b) >> 8;
                atomicOr(&sup32[r * 32 + (j >> 5)], 1u << (j & 31));
            }
        }
    }
    __syncthreads();
    for (int t = tid; t < 64; t += 256) {
        int r = t >> 4, w = t & 15;
        int i = b + (r << 8);
        sup[i * 16 + w] = (u64)sup32[r * 32 + 2 * w] |
                          ((u64)sup32[r * 32 + 2 * w + 1] << 32);
    }
}

// ---------------------------------------------------------------------------
// nms_sa: validated single-wave greedy NMS; 256-thread block, lanes >= 64
// idle but participate in barriers.
// ---------------------------------------------------------------------------
__global__ __launch_bounds__(256) void nms_sa_kernel(
        const u64* __restrict__ sup, const int* __restrict__ order,
        int* __restrict__ sampled) {
    __shared__ u64 bc[64];
    int tid = threadIdx.x;
    int lane = tid & 63;
    u64 kw[16], acc[16], row[16];
    if (tid < 64) {
#pragma unroll
        for (int t = 0; t < 16; ++t) acc[t] = 0ULL;
#pragma unroll
        for (int t = 0; t < 16; ++t) row[t] = sup[(size_t)lane * 16 + t];
    }
#pragma unroll
    for (int W = 0; W < 16; ++W) {
        u64 kwW = 0ULL;
        if (tid < 64) {
            u64 v = acc[W];
#pragma unroll
            for (int off = 32; off > 0; off >>= 1) v |= __shfl_xor(v, off, 64);
            kwW = ~v;
            bc[lane] = row[W];
        }
        __syncthreads();
        if (tid < 64) {
            u64 rowN[16];
#pragma unroll
            for (int t = 0; t < 16; ++t) rowN[t] = 0ULL;
            if (W < 15) {
#pragma unroll
                for (int t = 0; t < 16; ++t)
                    if (t >= W + 1)
                        rowN[t] = sup[(size_t)((W + 1) * 64 + lane) * 16 + t];
            }
#pragma unroll
            for (int bb = 0; bb < 64; ++bb) {
                bool kb = (kwW >> bb) & 1ULL;
                kwW &= kb ? ~bc[bb] : ~0ULL;
            }
            kw[W] = kwW;
            bool me = (kwW >> lane) & 1ULL;
#pragma unroll
            for (int t = W + 1; t < 16; ++t) acc[t] |= me ? row[t] : 0ULL;
#pragma unroll
            for (int t = 0; t < 16; ++t) row[t] = rowN[t];
        }
        __syncthreads();
    }
    if (tid < 64) {
#pragma unroll
        for (int t = 0; t < 16; ++t) {
            int idx = t * 64 + lane;
            sampled[order[idx]] = (int)((kw[t] >> lane) & 1ULL);
        }
    }
}

// ---------------------------------------------------------------------------
// outB_sa: block b owns pred rows i = b + 256v. sampled+circle scan -> LDS
// buffer (worst case 4096 = cap) -> dense IoU3D eval -> per-row packed
// (iou, 1023-j) u64 LDS atomicMax -> writes out[2], out[3].
// ---------------------------------------------------------------------------
__global__ __launch_bounds__(256) void outB_sa_kernel(
        const float* __restrict__ pred, const float* __restrict__ gt,
        const int* __restrict__ sampled, const float4* __restrict__ circ_p,
        const float4* __restrict__ circ_g, float* __restrict__ out) {
    __shared__ unsigned ring[4096];
    __shared__ unsigned cnt_s;
    __shared__ u64 rm[4];
    int tid = threadIdx.x;
    int b = blockIdx.x;
    int lane = tid & 63;
    int wv = tid >> 6;
    if (tid == 0) cnt_s = 0u;
    if (tid < 4) rm[tid] = 1023ULL;  // pack(iou=0.0f, j=0)
    __syncthreads();
    {
        int i = b + (wv << 8);
        float4 A = circ_p[i];
        for (int jb = 0; jb < 1024; jb += 64) {
            int j = jb + lane;
            bool q = sampled[j] != 0;
            if (q) {
                float4 B = circ_g[j];
                float dx = A.x - B.x, dy = A.y - B.y;
                float lim = A.z + B.z + 1e-3f;
                q = (dx * dx + dy * dy) <= lim * lim;
            }
            if (q) {
                unsigned pos = atomicAdd(&cnt_s, 1u);
                ring[pos] = (unsigned)((i << 10) | j);
            }
        }
    }
    __syncthreads();
    {
        unsigned n = cnt_s;
        for (unsigned t = tid; t < n; t += 256) {
            unsigned p = ring[t];
            int i = (p >> 10) & 1023, j = p & 1023;
            float Ax = pred[i * 7 + 0], Ay = pred[i * 7 + 1], Az = pred[i * 7 + 2];
            float Adx = pred[i * 7 + 3], Ady = pred[i * 7 + 4], Adz = pred[i * 7 + 5];
            float Ar = pred[i * 7 + 6];
            float Bx = gt[j * 8 + 0], By = gt[j * 8 + 1], Bz = gt[j * 8 + 2];
            float Bdx = gt[j * 8 + 3], Bdy = gt[j * 8 + 4], Bdz = gt[j * 8 + 5];
            float Br = gt[j * 8 + 6];
            float inter = rect_inter_area(Ax, Ay, Adx, Ady, Ar,
                                          Bx, By, Bdx, Bdy, Br);
            float amax = Az + Adz * 0.5f, amin = Az - Adz * 0.5f;
            float bmax = Bz + Bdz * 0.5f, bmin = Bz - Bdz * 0.5f;
            float oh = fmaxf(fminf(amax, bmax) - fmaxf(amin, bmin), 0.0f);
            float inter3d = inter * oh;
            float va = Adx * Ady * Adz, vb = Bdx * Bdy * Bdz;
            float iou = inter3d / fmaxf(va + vb - inter3d, 1e-8f);
            u64 pk = (((u64)__float_as_uint(iou)) << 32) | (u64)(1023 - j);
            int r = (i - b) >> 8;
            atomicMax(&rm[r], pk);
        }
    }
    __syncthreads();
    if (tid < 4) {
        int i = b + (tid << 8);
        u64 v = rm[tid];
        float fv = __uint_as_float((unsigned)(v >> 32));
        int j = 1023 - (int)(v & 0xFFFFFFFFULL);
        float mo = (fv > 0.75f) ? 1.0f : ((fv < 0.25f) ? 0.0f : fv);
        out[2 * NB + i] = mo;
        out[3 * NB + i] = (float)j;
    }
}

// ---------------------------------------------------------------------------
// Workspace layout:
//   [0,       4096)    int   order[1024]
//   [4096,    36864)   float sbox[1024*8]
//   [36864,   40960)   int   sampled[1024]
//   [40960,   172032)  u64   sup[1024*16]
//   [172032,  188416)  float4 circ_s[1024]
//   [188416,  204800)  float4 circ_g[1024]
//   [204800,  221184)  float4 circ_p[1024]
// ---------------------------------------------------------------------------
extern "C" void kernel_launch(void* const* d_in, const int* in_sizes, int n_in,
                              void* d_out, int out_size, void* d_ws, size_t ws_size,
                              hipStream_t stream) {
    const float* labels = (const float*)d_in[0];
    const float* pred   = (const float*)d_in[1];
    const float* gt     = (const float*)d_in[2];
    const float* cls    = (const float*)d_in[3];
    float* out = (float*)d_out;

    char* ws = (char*)d_ws;
    int* order     = (int*)ws;
    float* sbox    = (float*)(ws + 4096);
    int* sampled   = (int*)(ws + 36864);
    u64* sup       = (u64*)(ws + 40960);
    float4* circ_s = (float4*)(ws + 172032);
    float4* circ_g = (float4*)(ws + 188416);
    float4* circ_p = (float4*)(ws + 204800);

    prep_sa_kernel<<<256, 256, 0, stream>>>(labels, pred, gt, cls, out,
                                            order, sbox, circ_s, circ_g,
                                            circ_p);
    supA_sa_kernel<<<256, 256, 0, stream>>>(sbox, circ_s, sup);
    nms_sa_kernel<<<1, 256, 0, stream>>>(sup, order, sampled);
    outB_sa_kernel<<<256, 256, 0, stream>>>(pred, gt, sampled, circ_p,
                                            circ_g, out);
}

// Round 10
// 148.864 us; speedup vs baseline: 1.8281x; 1.0516x over previous
//
#include <hip/hip_runtime.h>
#include <math.h>

// ---------------------------------------------------------------------------
// PreLossSampler (N=1024):
//   out = [reg_valid | labels | max_overlaps | gt_assignment]  (4096 float32)
//
// 3 kernels (round-9 post-mortem: each kernel boundary ~10 us; grid.sync
// ~45 us — dead end; nms's LDS-broadcast chain was the 40 us hot spot):
//   prep_sa   : 256x256, wave-per-element stable rank sort; writes
//               rankinv[e] = sorted position (inverse perm), sbox, circles.
//   supA_sa   : 256x256, block owns 4 sorted rows; circle scan -> LDS pair
//               buffer -> dense clip eval -> LDS atomicOr -> global sup.
//   outB_fused: 256x256. Phase 1 (tid<64): greedy NMS recomputed REDUNDANTLY
//               per block (parallel, wall time = one nms). Intra-word scan
//               uses ffs + v_readlane (box b's row-word lives in lane b's
//               register; scan is wave-uniform -> readlane is legal and
//               ~15 cyc vs ~130 for LDS/bpermute broadcast). Uniform keep
//               words -> LDS ksh[16]. Phase 2: pred x gt scan testing
//               sampled via rankinv[j] bit lookup in ksh; circle reject ->
//               LDS buffer -> dense IoU3D eval -> packed u64 atomicMax ->
//               writes out[2], out[3].
//
// Exactness: identical arithmetic to the absmax-0.0-validated rounds 6-9
// (clip, circle reject, rank predicate, ffs-scan NMS [= round-4 validated
// formulation], max packing). sampled[j] == bit rankinv[j] of keep mask by
// construction.
// ---------------------------------------------------------------------------

#define NB 1024

typedef unsigned long long u64;

__device__ __forceinline__ bool pt_in_box(float px, float py,
        float bx, float by, float bdx, float bdy, float cs, float sn) {
    float dx = px - bx, dy = py - by;
    float lx = dx * cs + dy * sn;
    float ly = dy * cs - dx * sn;
    return (fabsf(lx) <= bdx * 0.5f + 1e-5f) && (fabsf(ly) <= bdy * 0.5f + 1e-5f);
}

__device__ __forceinline__ unsigned sortbits(float f) {
    unsigned u = __float_as_uint(f + 0.0f);
    return (u & 0x80000000u) ? ~u : (u | 0x80000000u);
}

// v_readlane on a u64 (lane index wave-uniform; scan loop is uniform).
__device__ __forceinline__ u64 readlane64(u64 v, int lane) {
    unsigned lo = (unsigned)__builtin_amdgcn_readlane((int)(unsigned)v, lane);
    unsigned hi =
        (unsigned)__builtin_amdgcn_readlane((int)(unsigned)(v >> 32), lane);
    return ((u64)hi << 32) | (u64)lo;
}

// Rotated-rectangle intersection area; reference-exact op order; all arrays
// <= 96 B, statically indexed (register-resident, zero scratch).
// Validated absmax 0.0.
__device__ float rect_inter_area(
        float ax, float ay, float adx, float ady, float ar,
        float bx, float by, float bdx, float bdy, float br) {
    float dcx = ax - bx, dcy = ay - by;
    float ra = 0.5f * sqrtf(adx * adx + ady * ady);
    float rb = 0.5f * sqrtf(bdx * bdx + bdy * bdy);
    float lim = ra + rb + 1e-3f;
    if (dcx * dcx + dcy * dcy > lim * lim) return 0.0f;

    float csa = cosf(ar), sna = sinf(ar);
    float csb = cosf(br), snb = sinf(br);
    float cax[4], cay[4], cbx[4], cby[4];
    const float SX[4] = {0.5f, 0.5f, -0.5f, -0.5f};
    const float SY[4] = {0.5f, -0.5f, -0.5f, 0.5f};
#pragma unroll
    for (int i = 0; i < 4; ++i) {
        float lx = SX[i] * adx, ly = SY[i] * ady;
        cax[i] = lx * csa - ly * sna + ax;
        cay[i] = lx * sna + ly * csa + ay;
        float mx = SX[i] * bdx, my = SY[i] * bdy;
        cbx[i] = mx * csb - my * snb + bx;
        cby[i] = mx * snb + my * csb + by;
    }

    unsigned vmask = 0u;
    float sx = 0.0f, sy = 0.0f;
#pragma unroll
    for (int i = 0; i < 4; ++i) {
        bool v = pt_in_box(cax[i], cay[i], bx, by, bdx, bdy, csb, snb);
        vmask |= v ? (1u << i) : 0u;
        sx += v ? cax[i] : 0.0f;
        sy += v ? cay[i] : 0.0f;
    }
#pragma unroll
    for (int i = 0; i < 4; ++i) {
        bool v = pt_in_box(cbx[i], cby[i], ax, ay, adx, ady, csa, sna);
        vmask |= v ? (1u << (4 + i)) : 0u;
        sx += v ? cbx[i] : 0.0f;
        sy += v ? cby[i] : 0.0f;
    }
#pragma unroll
    for (int i = 0; i < 4; ++i) {
        float a0x = cax[i], a0y = cay[i];
        float d1x = cax[(i + 1) & 3] - a0x, d1y = cay[(i + 1) & 3] - a0y;
#pragma unroll
        for (int j = 0; j < 4; ++j) {
            int s = 8 + i * 4 + j;
            float b0x = cbx[j], b0y = cby[j];
            float d2x = cbx[(j + 1) & 3] - b0x, d2y = cby[(j + 1) & 3] - b0y;
            float r0x = b0x - a0x, r0y = b0y - a0y;
            float den = d1x * d2y - d1y * d2x;
            bool nz = fabsf(den) > 1e-8f;
            float sden = nz ? den : 1.0f;
            float t = (r0x * d2y - r0y * d2x) / sden;
            float u = (r0x * d1y - r0y * d1x) / sden;
            bool ok = nz && t >= 0.0f && t <= 1.0f && u >= 0.0f && u <= 1.0f;
            float ipx = a0x + t * d1x;
            float ipy = a0y + t * d1y;
            vmask |= ok ? (1u << s) : 0u;
            sx += ok ? ipx : 0.0f;
            sy += ok ? ipy : 0.0f;
        }
    }
    int kc = __popc(vmask);
    if (kc < 3) return 0.0f;
    float ctrx = sx / (float)kc, ctry = sy / (float)kc;

    float cx24[24], cy24[24];
    unsigned h[24];
#pragma unroll
    for (int i = 0; i < 4; ++i) {
        {
            bool v = (vmask >> i) & 1u;
            float cx = v ? cax[i] - ctrx : 0.0f;
            float cy = v ? cay[i] - ctry : 0.0f;
            cx24[i] = cx; cy24[i] = cy;
            h[i] = sortbits(v ? atan2f(cy, cx) : 1e9f);
        }
        {
            bool v = (vmask >> (4 + i)) & 1u;
            float cx = v ? cbx[i] - ctrx : 0.0f;
            float cy = v ? cby[i] - ctry : 0.0f;
            cx24[4 + i] = cx; cy24[4 + i] = cy;
            h[4 + i] = sortbits(v ? atan2f(cy, cx) : 1e9f);
        }
    }
#pragma unroll
    for (int i = 0; i < 4; ++i) {
        float a0x = cax[i], a0y = cay[i];
        float d1x = cax[(i + 1) & 3] - a0x, d1y = cay[(i + 1) & 3] - a0y;
#pragma unroll
        for (int j = 0; j < 4; ++j) {
            int s = 8 + i * 4 + j;
            float b0x = cbx[j], b0y = cby[j];
            float d2x = cbx[(j + 1) & 3] - b0x, d2y = cby[(j + 1) & 3] - b0y;
            float r0x = b0x - a0x, r0y = b0y - a0y;
            float den = d1x * d2y - d1y * d2x;
            bool nz = fabsf(den) > 1e-8f;
            float sden = nz ? den : 1.0f;
            float t = (r0x * d2y - r0y * d2x) / sden;
            bool v = (vmask >> s) & 1u;
            float ipx = a0x + t * d1x;
            float ipy = a0y + t * d1y;
            float cx = v ? ipx - ctrx : 0.0f;
            float cy = v ? ipy - ctry : 0.0f;
            cx24[s] = cx; cy24[s] = cy;
            h[s] = sortbits(v ? atan2f(cy, cx) : 1e9f);
        }
    }

    int rk[24];
#pragma unroll
    for (int s = 0; s < 24; ++s) rk[s] = 0;
#pragma unroll
    for (int s = 0; s < 24; ++s) {
#pragma unroll
        for (int t = s + 1; t < 24; ++t) {
            bool a = h[s] <= h[t];
            rk[t] += a ? 1 : 0;
            rk[s] += a ? 0 : 1;
        }
    }

    float acc = 0.0f;
    float fx = 0.0f, fy = 0.0f, lx2 = 0.0f, ly2 = 0.0f;
    float pxp = 0.0f, pyp = 0.0f;
#pragma unroll
    for (int p = 0; p < 24; ++p) {
        float X = 0.0f, Y = 0.0f;
#pragma unroll
        for (int s = 0; s < 24; ++s) {
            bool m = (rk[s] == p);
            X = m ? cx24[s] : X;
            Y = m ? cy24[s] : Y;
        }
        if (p == 0) {
            fx = X; fy = Y;
        } else {
            float cr = pxp * Y - pyp * X;
            acc += (p < kc) ? cr : 0.0f;
        }
        bool e = (p == kc - 1);
        lx2 = e ? X : lx2;
        ly2 = e ? Y : ly2;
        pxp = X; pyp = Y;
    }
    acc += lx2 * fy - ly2 * fx;
    return 0.5f * fabsf(acc);
}

// ---------------------------------------------------------------------------
// prep_sa: 256x256. Wave (global id) handles element e; lane counts 16 keys;
// butterfly sum -> stable rank. Writes rankinv[e]=rank (inverse perm),
// sorted sbox/circ_s, circles, elementwise outs.
// ---------------------------------------------------------------------------
__global__ __launch_bounds__(256) void prep_sa_kernel(
        const float* __restrict__ labels, const float* __restrict__ pred,
        const float* __restrict__ gt, const float* __restrict__ cls,
        float* __restrict__ out, int* __restrict__ rankinv,
        float* __restrict__ sbox, float4* __restrict__ circ_s,
        float4* __restrict__ circ_g, float4* __restrict__ circ_p) {
    int tid = threadIdx.x;
    int lane = tid & 63;
    int e = ((int)blockIdx.x * 256 + tid) >> 6;  // global wave id = element
    float ke = labels[e];
    const float4* lab4 = (const float4*)labels;
    int cntr = 0;
#pragma unroll
    for (int kk = 0; kk < 4; ++kk) {
        float4 kv = lab4[lane * 4 + kk];
        int t0 = lane * 16 + kk * 4;
        cntr += ((kv.x > ke) || (kv.x == ke && (t0 + 0) < e)) ? 1 : 0;
        cntr += ((kv.y > ke) || (kv.y == ke && (t0 + 1) < e)) ? 1 : 0;
        cntr += ((kv.z > ke) || (kv.z == ke && (t0 + 2) < e)) ? 1 : 0;
        cntr += ((kv.w > ke) || (kv.w == ke && (t0 + 3) < e)) ? 1 : 0;
    }
#pragma unroll
    for (int off = 32; off > 0; off >>= 1) cntr += __shfl_xor(cntr, off, 64);
    int rank = cntr;  // stable argsort(-labels) position of e
    if (lane < 7) sbox[rank * 8 + lane] = gt[e * 8 + lane];
    if (lane == 7) sbox[rank * 8 + 7] = 0.0f;
    if (lane == 0) {
        rankinv[e] = rank;
        float gdx = gt[e * 8 + 3], gdy = gt[e * 8 + 4];
        float4 cgc = make_float4(gt[e * 8 + 0], gt[e * 8 + 1],
                                 0.5f * sqrtf(gdx * gdx + gdy * gdy), 0.0f);
        circ_s[rank] = cgc;
        circ_g[e] = cgc;
        float pdx = pred[e * 7 + 3], pdy = pred[e * 7 + 4];
        circ_p[e] = make_float4(pred[e * 7 + 0], pred[e * 7 + 1],
                                0.5f * sqrtf(pdx * pdx + pdy * pdy), 0.0f);
        float sig = 1.0f / (1.0f + expf(-cls[e]));
        out[e] = (sig > 0.55f && ke > 0.55f) ? 1.0f : 0.0f;
        out[NB + e] = ke;
    }
}

// ---------------------------------------------------------------------------
// supA_sa: block b owns sorted rows i = b + 256v (v = wave). Circle scan ->
// LDS buffer (worst case 2556 <= 4096) -> dense clip eval -> LDS atomicOr ->
// global sup (all 16 words of all 4 rows written). Validated round 9.
// ---------------------------------------------------------------------------
__global__ __launch_bounds__(256) void supA_sa_kernel(
        const float* __restrict__ sbox, const float4* __restrict__ circ_s,
        u64* __restrict__ sup) {
    __shared__ unsigned ring[4096];
    __shared__ unsigned cnt_s;
    __shared__ unsigned sup32[128];
    int tid = threadIdx.x;
    int b = blockIdx.x;
    int lane = tid & 63;
    int wv = tid >> 6;
    if (tid == 0) cnt_s = 0u;
    for (int t = tid; t < 128; t += 256) sup32[t] = 0u;
    __syncthreads();
    {
        int i = b + (wv << 8);
        float4 A = circ_s[i];
        int j0 = ((i + 1) >> 6) << 6;
        for (int jb = j0; jb < 1024; jb += 64) {
            int j = jb + lane;
            bool q = j > i;
            if (q) {
                float4 B = circ_s[j];
                float dx = A.x - B.x, dy = A.y - B.y;
                float lim = A.z + B.z + 1e-3f;
                q = (dx * dx + dy * dy) <= lim * lim;
            }
            if (q) {
                unsigned pos = atomicAdd(&cnt_s, 1u);
                ring[pos] = (unsigned)((i << 10) | j);
            }
        }
    }
    __syncthreads();
    {
        unsigned n = cnt_s;
        for (unsigned t = tid; t < n; t += 256) {
            unsigned p = ring[t];
            int i = (p >> 10) & 1023, j = p & 1023;
            const float* A = &sbox[i * 8];
            const float* B = &sbox[j * 8];
            float inter = rect_inter_area(A[0], A[1], A[3], A[4], A[6],
                                          B[0], B[1], B[3], B[4], B[6]);
            float iou = inter / fmaxf(A[3] * A[4] + B[3] * B[4] - inter, 1e-8f);
            if (iou > 0.1f) {
                int r = (i - b) >> 8;
                atomicOr(&sup32[r * 32 + (j >> 5)], 1u << (j & 31));
            }
        }
    }
    __syncthreads();
    for (int t = tid; t < 64; t += 256) {
        int r = t >> 4, w = t & 15;
        int i = b + (r << 8);
        sup[i * 16 + w] = (u64)sup32[r * 32 + 2 * w] |
                          ((u64)sup32[r * 32 + 2 * w + 1] << 32);
    }
}

// ---------------------------------------------------------------------------
// outB_fused: phase 1 (tid<64) = greedy NMS redundantly per block (wall time
// = one nms; ffs+readlane chain, no LDS broadcast, no per-word barriers);
// keep words -> ksh[16]. Phase 2 = pred x gt scan (sampled via rankinv bit
// lookup) -> LDS buffer -> dense IoU3D eval -> packed u64 atomicMax ->
// out[2], out[3].
// ---------------------------------------------------------------------------
__global__ __launch_bounds__(256) void outB_fused_kernel(
        const float* __restrict__ pred, const float* __restrict__ gt,
        const int* __restrict__ rankinv, const float4* __restrict__ circ_p,
        const float4* __restrict__ circ_g, const u64* __restrict__ sup,
        float* __restrict__ out) {
    __shared__ unsigned ring[4096];
    __shared__ unsigned cnt_s;
    __shared__ u64 ksh[16];
    __shared__ u64 rm[4];
    int tid = threadIdx.x;
    int b = blockIdx.x;
    int lane = tid & 63;
    int wv = tid >> 6;
    if (tid == 0) cnt_s = 0u;
    if (tid < 4) rm[tid] = 1023ULL;  // pack(iou=0.0f, j=0)

    // ---- phase 1: NMS (wave 0 only; uniform scan, readlane broadcast) ----
    if (tid < 64) {
        u64 acc[16];
        u64 row[16];
#pragma unroll
        for (int t = 0; t < 16; ++t) acc[t] = 0ULL;
#pragma unroll
        for (int t = 0; t < 16; ++t) row[t] = sup[(size_t)lane * 16 + t];
#pragma unroll
        for (int W = 0; W < 16; ++W) {
            u64 kwW;
            if (W == 0) {
                kwW = ~0ULL;  // no prior words
            } else {
                u64 v = acc[W];
#pragma unroll
                for (int off = 32; off > 0; off >>= 1)
                    v |= __shfl_xor(v, off, 64);
                kwW = ~v;
            }
            // prefetch next word-block's rows (overlaps the chain)
            u64 rowN[16];
#pragma unroll
            for (int t = 0; t < 16; ++t) rowN[t] = 0ULL;
            if (W < 15) {
#pragma unroll
                for (int t = 0; t < 16; ++t)
                    if (t >= W + 1)
                        rowN[t] = sup[(size_t)((W + 1) * 64 + lane) * 16 + t];
            }
            // intra-word greedy: ffs + readlane (box bb's row-word W lives
            // in lane bb's row[W]; bits of rb are all > bb)
            u64 rem = kwW;
            while (rem) {
                int bb = __ffsll(rem) - 1;         // wave-uniform
                u64 rb = readlane64(row[W], bb);
                kwW &= ~rb;
                rem = (bb >= 63) ? 0ULL : (kwW & (~0ULL << (bb + 1)));
            }
            if (lane == 0) ksh[W] = kwW;
            bool me = (kwW >> lane) & 1ULL;
#pragma unroll
            for (int t = W + 1; t < 16; ++t) acc[t] |= me ? row[t] : 0ULL;
#pragma unroll
            for (int t = 0; t < 16; ++t) row[t] = rowN[t];
        }
    }
    __syncthreads();

    // ---- phase 2: scan + eval ----
    {
        int i = b + (wv << 8);
        float4 A = circ_p[i];
        for (int jb = 0; jb < 1024; jb += 64) {
            int j = jb + lane;
            int r = rankinv[j];
            bool q = (ksh[r >> 6] >> (r & 63)) & 1ULL;  // sampled[j]
            if (q) {
                float4 B = circ_g[j];
                float dx = A.x - B.x, dy = A.y - B.y;
                float lim = A.z + B.z + 1e-3f;
                q = (dx * dx + dy * dy) <= lim * lim;
            }
            if (q) {
                unsigned pos = atomicAdd(&cnt_s, 1u);
                ring[pos] = (unsigned)((i << 10) | j);
            }
        }
    }
    __syncthreads();
    {
        unsigned n = cnt_s;
        for (unsigned t = tid; t < n; t += 256) {
            unsigned p = ring[t];
            int i = (p >> 10) & 1023, j = p & 1023;
            float Ax = pred[i * 7 + 0], Ay = pred[i * 7 + 1], Az = pred[i * 7 + 2];
            float Adx = pred[i * 7 + 3], Ady = pred[i * 7 + 4], Adz = pred[i * 7 + 5];
            float Ar = pred[i * 7 + 6];
            float Bx = gt[j * 8 + 0], By = gt[j * 8 + 1], Bz = gt[j * 8 + 2];
            float Bdx = gt[j * 8 + 3], Bdy = gt[j * 8 + 4], Bdz = gt[j * 8 + 5];
            float Br = gt[j * 8 + 6];
            float inter = rect_inter_area(Ax, Ay, Adx, Ady, Ar,
                                          Bx, By, Bdx, Bdy, Br);
            float amax = Az + Adz * 0.5f, amin = Az - Adz * 0.5f;
            float bmax = Bz + Bdz * 0.5f, bmin = Bz - Bdz * 0.5f;
            float oh = fmaxf(fminf(amax, bmax) - fmaxf(amin, bmin), 0.0f);
            float inter3d = inter * oh;
            float va = Adx * Ady * Adz, vb = Bdx * Bdy * Bdz;
            float iou = inter3d / fmaxf(va + vb - inter3d, 1e-8f);
            u64 pk = (((u64)__float_as_uint(iou)) << 32) | (u64)(1023 - j);
            int r = (i - b) >> 8;
            atomicMax(&rm[r], pk);
        }
    }
    __syncthreads();
    if (tid < 4) {
        int i = b + (tid << 8);
        u64 v = rm[tid];
        float fv = __uint_as_float((unsigned)(v >> 32));
        int j = 1023 - (int)(v & 0xFFFFFFFFULL);
        float mo = (fv > 0.75f) ? 1.0f : ((fv < 0.25f) ? 0.0f : fv);
        out[2 * NB + i] = mo;
        out[3 * NB + i] = (float)j;
    }
}

// ---------------------------------------------------------------------------
// Workspace layout:
//   [0,       4096)    int   rankinv[1024]
//   [4096,    36864)   float sbox[1024*8]
//   [36864,   40960)   (unused)
//   [40960,   172032)  u64   sup[1024*16]
//   [172032,  188416)  float4 circ_s[1024]
//   [188416,  204800)  float4 circ_g[1024]
//   [204800,  221184)  float4 circ_p[1024]
// ---------------------------------------------------------------------------
extern "C" void kernel_launch(void* const* d_in, const int* in_sizes, int n_in,
                              void* d_out, int out_size, void* d_ws, size_t ws_size,
                              hipStream_t stream) {
    const float* labels = (const float*)d_in[0];
    const float* pred   = (const float*)d_in[1];
    const float* gt     = (const float*)d_in[2];
    const float* cls    = (const float*)d_in[3];
    float* out = (float*)d_out;

    char* ws = (char*)d_ws;
    int* rankinv   = (int*)ws;
    float* sbox    = (float*)(ws + 4096);
    u64* sup       = (u64*)(ws + 40960);
    float4* circ_s = (float4*)(ws + 172032);
    float4* circ_g = (float4*)(ws + 188416);
    float4* circ_p = (float4*)(ws + 204800);

    prep_sa_kernel<<<256, 256, 0, stream>>>(labels, pred, gt, cls, out,
                                            rankinv, sbox, circ_s, circ_g,
                                            circ_p);
    supA_sa_kernel<<<256, 256, 0, stream>>>(sbox, circ_s, sup);
    outB_fused_kernel<<<256, 256, 0, stream>>>(pred, gt, rankinv, circ_p,
                                               circ_g, sup, out);
}

// Round 11
// 145.479 us; speedup vs baseline: 1.8707x; 1.0233x over previous
//
#include <hip/hip_runtime.h>
#include <math.h>

// ---------------------------------------------------------------------------
// PreLossSampler (N=1024):
//   out = [reg_valid | labels | max_overlaps | gt_assignment]  (4096 float32)
//
// 3 kernels:
//   prep_sa   : 256x256, wave-per-element stable rank sort; writes
//               rankinv[e], sorted sbox/circ_s, circles, elementwise outs.
//   supA_sa   : 256x256, block owns 4 sorted rows; circle scan -> LDS pair
//               buffer -> dense clip eval -> LDS atomicOr -> global sup.
//   outB_fused: 256x256. Phase 1 (wave 0): greedy NMS recomputed redundantly
//               per block. Per word: LDS broadcast bc[lane]=row[W] (same-wave
//               ordering, no barrier), then 4 batches of {16 ds_read_b64 ->
//               16 VALU cndmask steps} — amortizes LDS latency (round 9 read
//               inline = ~130 cyc/step = 40 us; round 10's readlane hit a
//               compiler waterfall = ~50 us). Keep words -> ksh[16].
//               Phase 2: pred x gt scan (sampled via rankinv bit lookup) ->
//               LDS buffer -> dense IoU3D eval -> packed u64 atomicMax ->
//               out[2], out[3].
//
// Exactness: identical arithmetic to the absmax-0.0-validated rounds 6-10
// (clip, circle reject, rank predicate, 64-step cndmask NMS chain [round 9
// validated; only read grouping changed], max packing).
// ---------------------------------------------------------------------------

#define NB 1024

typedef unsigned long long u64;

__device__ __forceinline__ bool pt_in_box(float px, float py,
        float bx, float by, float bdx, float bdy, float cs, float sn) {
    float dx = px - bx, dy = py - by;
    float lx = dx * cs + dy * sn;
    float ly = dy * cs - dx * sn;
    return (fabsf(lx) <= bdx * 0.5f + 1e-5f) && (fabsf(ly) <= bdy * 0.5f + 1e-5f);
}

__device__ __forceinline__ unsigned sortbits(float f) {
    unsigned u = __float_as_uint(f + 0.0f);
    return (u & 0x80000000u) ? ~u : (u | 0x80000000u);
}

// Rotated-rectangle intersection area; reference-exact op order; all arrays
// <= 96 B, statically indexed (register-resident, zero scratch).
// Validated absmax 0.0.
__device__ float rect_inter_area(
        float ax, float ay, float adx, float ady, float ar,
        float bx, float by, float bdx, float bdy, float br) {
    float dcx = ax - bx, dcy = ay - by;
    float ra = 0.5f * sqrtf(adx * adx + ady * ady);
    float rb = 0.5f * sqrtf(bdx * bdx + bdy * bdy);
    float lim = ra + rb + 1e-3f;
    if (dcx * dcx + dcy * dcy > lim * lim) return 0.0f;

    float csa = cosf(ar), sna = sinf(ar);
    float csb = cosf(br), snb = sinf(br);
    float cax[4], cay[4], cbx[4], cby[4];
    const float SX[4] = {0.5f, 0.5f, -0.5f, -0.5f};
    const float SY[4] = {0.5f, -0.5f, -0.5f, 0.5f};
#pragma unroll
    for (int i = 0; i < 4; ++i) {
        float lx = SX[i] * adx, ly = SY[i] * ady;
        cax[i] = lx * csa - ly * sna + ax;
        cay[i] = lx * sna + ly * csa + ay;
        float mx = SX[i] * bdx, my = SY[i] * bdy;
        cbx[i] = mx * csb - my * snb + bx;
        cby[i] = mx * snb + my * csb + by;
    }

    unsigned vmask = 0u;
    float sx = 0.0f, sy = 0.0f;
#pragma unroll
    for (int i = 0; i < 4; ++i) {
        bool v = pt_in_box(cax[i], cay[i], bx, by, bdx, bdy, csb, snb);
        vmask |= v ? (1u << i) : 0u;
        sx += v ? cax[i] : 0.0f;
        sy += v ? cay[i] : 0.0f;
    }
#pragma unroll
    for (int i = 0; i < 4; ++i) {
        bool v = pt_in_box(cbx[i], cby[i], ax, ay, adx, ady, csa, sna);
        vmask |= v ? (1u << (4 + i)) : 0u;
        sx += v ? cbx[i] : 0.0f;
        sy += v ? cby[i] : 0.0f;
    }
#pragma unroll
    for (int i = 0; i < 4; ++i) {
        float a0x = cax[i], a0y = cay[i];
        float d1x = cax[(i + 1) & 3] - a0x, d1y = cay[(i + 1) & 3] - a0y;
#pragma unroll
        for (int j = 0; j < 4; ++j) {
            int s = 8 + i * 4 + j;
            float b0x = cbx[j], b0y = cby[j];
            float d2x = cbx[(j + 1) & 3] - b0x, d2y = cby[(j + 1) & 3] - b0y;
            float r0x = b0x - a0x, r0y = b0y - a0y;
            float den = d1x * d2y - d1y * d2x;
            bool nz = fabsf(den) > 1e-8f;
            float sden = nz ? den : 1.0f;
            float t = (r0x * d2y - r0y * d2x) / sden;
            float u = (r0x * d1y - r0y * d1x) / sden;
            bool ok = nz && t >= 0.0f && t <= 1.0f && u >= 0.0f && u <= 1.0f;
            float ipx = a0x + t * d1x;
            float ipy = a0y + t * d1y;
            vmask |= ok ? (1u << s) : 0u;
            sx += ok ? ipx : 0.0f;
            sy += ok ? ipy : 0.0f;
        }
    }
    int kc = __popc(vmask);
    if (kc < 3) return 0.0f;
    float ctrx = sx / (float)kc, ctry = sy / (float)kc;

    float cx24[24], cy24[24];
    unsigned h[24];
#pragma unroll
    for (int i = 0; i < 4; ++i) {
        {
            bool v = (vmask >> i) & 1u;
            float cx = v ? cax[i] - ctrx : 0.0f;
            float cy = v ? cay[i] - ctry : 0.0f;
            cx24[i] = cx; cy24[i] = cy;
            h[i] = sortbits(v ? atan2f(cy, cx) : 1e9f);
        }
        {
            bool v = (vmask >> (4 + i)) & 1u;
            float cx = v ? cbx[i] - ctrx : 0.0f;
            float cy = v ? cby[i] - ctry : 0.0f;
            cx24[4 + i] = cx; cy24[4 + i] = cy;
            h[4 + i] = sortbits(v ? atan2f(cy, cx) : 1e9f);
        }
    }
#pragma unroll
    for (int i = 0; i < 4; ++i) {
        float a0x = cax[i], a0y = cay[i];
        float d1x = cax[(i + 1) & 3] - a0x, d1y = cay[(i + 1) & 3] - a0y;
#pragma unroll
        for (int j = 0; j < 4; ++j) {
            int s = 8 + i * 4 + j;
            float b0x = cbx[j], b0y = cby[j];
            float d2x = cbx[(j + 1) & 3] - b0x, d2y = cby[(j + 1) & 3] - b0y;
            float r0x = b0x - a0x, r0y = b0y - a0y;
            float den = d1x * d2y - d1y * d2x;
            bool nz = fabsf(den) > 1e-8f;
            float sden = nz ? den : 1.0f;
            float t = (r0x * d2y - r0y * d2x) / sden;
            bool v = (vmask >> s) & 1u;
            float ipx = a0x + t * d1x;
            float ipy = a0y + t * d1y;
            float cx = v ? ipx - ctrx : 0.0f;
            float cy = v ? ipy - ctry : 0.0f;
            cx24[s] = cx; cy24[s] = cy;
            h[s] = sortbits(v ? atan2f(cy, cx) : 1e9f);
        }
    }

    int rk[24];
#pragma unroll
    for (int s = 0; s < 24; ++s) rk[s] = 0;
#pragma unroll
    for (int s = 0; s < 24; ++s) {
#pragma unroll
        for (int t = s + 1; t < 24; ++t) {
            bool a = h[s] <= h[t];
            rk[t] += a ? 1 : 0;
            rk[s] += a ? 0 : 1;
        }
    }

    float acc = 0.0f;
    float fx = 0.0f, fy = 0.0f, lx2 = 0.0f, ly2 = 0.0f;
    float pxp = 0.0f, pyp = 0.0f;
#pragma unroll
    for (int p = 0; p < 24; ++p) {
        float X = 0.0f, Y = 0.0f;
#pragma unroll
        for (int s = 0; s < 24; ++s) {
            bool m = (rk[s] == p);
            X = m ? cx24[s] : X;
            Y = m ? cy24[s] : Y;
        }
        if (p == 0) {
            fx = X; fy = Y;
        } else {
            float cr = pxp * Y - pyp * X;
            acc += (p < kc) ? cr : 0.0f;
        }
        bool e = (p == kc - 1);
        lx2 = e ? X : lx2;
        ly2 = e ? Y : ly2;
        pxp = X; pyp = Y;
    }
    acc += lx2 * fy - ly2 * fx;
    return 0.5f * fabsf(acc);
}

// ---------------------------------------------------------------------------
// prep_sa: 256x256. Wave (global id) handles element e; lane counts 16 keys;
// butterfly sum -> stable rank. Writes rankinv[e]=rank, sorted sbox/circ_s,
// circles, elementwise outs. (Validated round 9/10.)
// ---------------------------------------------------------------------------
__global__ __launch_bounds__(256) void prep_sa_kernel(
        const float* __restrict__ labels, const float* __restrict__ pred,
        const float* __restrict__ gt, const float* __restrict__ cls,
        float* __restrict__ out, int* __restrict__ rankinv,
        float* __restrict__ sbox, float4* __restrict__ circ_s,
        float4* __restrict__ circ_g, float4* __restrict__ circ_p) {
    int tid = threadIdx.x;
    int lane = tid & 63;
    int e = ((int)blockIdx.x * 256 + tid) >> 6;  // global wave id = element
    float ke = labels[e];
    const float4* lab4 = (const float4*)labels;
    int cntr = 0;
#pragma unroll
    for (int kk = 0; kk < 4; ++kk) {
        float4 kv = lab4[lane * 4 + kk];
        int t0 = lane * 16 + kk * 4;
        cntr += ((kv.x > ke) || (kv.x == ke && (t0 + 0) < e)) ? 1 : 0;
        cntr += ((kv.y > ke) || (kv.y == ke && (t0 + 1) < e)) ? 1 : 0;
        cntr += ((kv.z > ke) || (kv.z == ke && (t0 + 2) < e)) ? 1 : 0;
        cntr += ((kv.w > ke) || (kv.w == ke && (t0 + 3) < e)) ? 1 : 0;
    }
#pragma unroll
    for (int off = 32; off > 0; off >>= 1) cntr += __shfl_xor(cntr, off, 64);
    int rank = cntr;  // stable argsort(-labels) position of e
    if (lane < 7) sbox[rank * 8 + lane] = gt[e * 8 + lane];
    if (lane == 7) sbox[rank * 8 + 7] = 0.0f;
    if (lane == 0) {
        rankinv[e] = rank;
        float gdx = gt[e * 8 + 3], gdy = gt[e * 8 + 4];
        float4 cgc = make_float4(gt[e * 8 + 0], gt[e * 8 + 1],
                                 0.5f * sqrtf(gdx * gdx + gdy * gdy), 0.0f);
        circ_s[rank] = cgc;
        circ_g[e] = cgc;
        float pdx = pred[e * 7 + 3], pdy = pred[e * 7 + 4];
        circ_p[e] = make_float4(pred[e * 7 + 0], pred[e * 7 + 1],
                                0.5f * sqrtf(pdx * pdx + pdy * pdy), 0.0f);
        float sig = 1.0f / (1.0f + expf(-cls[e]));
        out[e] = (sig > 0.55f && ke > 0.55f) ? 1.0f : 0.0f;
        out[NB + e] = ke;
    }
}

// ---------------------------------------------------------------------------
// supA_sa: block b owns sorted rows i = b + 256v (v = wave). Circle scan ->
// LDS buffer (worst case 2556 <= 4096) -> dense clip eval -> LDS atomicOr ->
// global sup (all 16 words of all 4 rows written). Validated round 9/10.
// ---------------------------------------------------------------------------
__global__ __launch_bounds__(256) void supA_sa_kernel(
        const float* __restrict__ sbox, const float4* __restrict__ circ_s,
        u64* __restrict__ sup) {
    __shared__ unsigned ring[4096];
    __shared__ unsigned cnt_s;
    __shared__ unsigned sup32[128];
    int tid = threadIdx.x;
    int b = blockIdx.x;
    int lane = tid & 63;
    int wv = tid >> 6;
    if (tid == 0) cnt_s = 0u;
    for (int t = tid; t < 128; t += 256) sup32[t] = 0u;
    __syncthreads();
    {
        int i = b + (wv << 8);
        float4 A = circ_s[i];
        int j0 = ((i + 1) >> 6) << 6;
        for (int jb = j0; jb < 1024; jb += 64) {
            int j = jb + lane;
            bool q = j > i;
            if (q) {
                float4 B = circ_s[j];
                float dx = A.x - B.x, dy = A.y - B.y;
                float lim = A.z + B.z + 1e-3f;
                q = (dx * dx + dy * dy) <= lim * lim;
            }
            if (q) {
                unsigned pos = atomicAdd(&cnt_s, 1u);
                ring[pos] = (unsigned)((i << 10) | j);
            }
        }
    }
    __syncthreads();
    {
        unsigned n = cnt_s;
        for (unsigned t = tid; t < n; t += 256) {
            unsigned p = ring[t];
            int i = (p >> 10) & 1023, j = p & 1023;
            const float* A = &sbox[i * 8];
            const float* B = &sbox[j * 8];
            float inter = rect_inter_area(A[0], A[1], A[3], A[4], A[6],
                                          B[0], B[1], B[3], B[4], B[6]);
            float iou = inter / fmaxf(A[3] * A[4] + B[3] * B[4] - inter, 1e-8f);
            if (iou > 0.1f) {
                int r = (i - b) >> 8;
                atomicOr(&sup32[r * 32 + (j >> 5)], 1u << (j & 31));
            }
        }
    }
    __syncthreads();
    for (int t = tid; t < 64; t += 256) {
        int r = t >> 4, w = t & 15;
        int i = b + (r << 8);
        sup[i * 16 + w] = (u64)sup32[r * 32 + 2 * w] |
                          ((u64)sup32[r * 32 + 2 * w + 1] << 32);
    }
}

// ---------------------------------------------------------------------------
// outB_fused: phase 1 (wave 0) = greedy NMS, redundant per block. Per word:
// bc[lane]=row[W] (same-wave LDS, no barrier), 4 batches of {16 ds_read ->
// 16 cndmask chain steps}. Phase 2 = pred x gt scan (sampled via rankinv
// bit lookup in ksh) -> LDS buffer -> dense IoU3D eval -> packed u64
// atomicMax -> out[2], out[3].
// ---------------------------------------------------------------------------
__global__ __launch_bounds__(256) void outB_fused_kernel(
        const float* __restrict__ pred, const float* __restrict__ gt,
        const int* __restrict__ rankinv, const float4* __restrict__ circ_p,
        const float4* __restrict__ circ_g, const u64* __restrict__ sup,
        float* __restrict__ out) {
    __shared__ unsigned ring[4096];
    __shared__ unsigned cnt_s;
    __shared__ u64 bc[64];
    __shared__ u64 ksh[16];
    __shared__ u64 rm[4];
    int tid = threadIdx.x;
    int b = blockIdx.x;
    int lane = tid & 63;
    int wv = tid >> 6;
    if (tid == 0) cnt_s = 0u;
    if (tid < 4) rm[tid] = 1023ULL;  // pack(iou=0.0f, j=0)

    // ---- phase 1: NMS (wave 0 only; no barriers inside the word loop) ----
    if (tid < 64) {
        u64 acc[16];
        u64 row[16];
#pragma unroll
        for (int t = 0; t < 16; ++t) acc[t] = 0ULL;
#pragma unroll
        for (int t = 0; t < 16; ++t) row[t] = sup[(size_t)lane * 16 + t];
#pragma unroll
        for (int W = 0; W < 16; ++W) {
            u64 kwW;
            if (W == 0) {
                kwW = ~0ULL;  // no prior words
            } else {
                u64 v = acc[W];
#pragma unroll
                for (int off = 32; off > 0; off >>= 1)
                    v |= __shfl_xor(v, off, 64);
                kwW = ~v;
            }
            // broadcast this word's 64 row-words (same-wave LDS: compiler
            // orders write->read via lgkmcnt; single wave, no barrier)
            bc[lane] = row[W];
            // prefetch next word-block's rows (overlaps the chain)
            u64 rowN[16];
#pragma unroll
            for (int t = 0; t < 16; ++t) rowN[t] = 0ULL;
            if (W < 15) {
#pragma unroll
                for (int t = 0; t < 16; ++t)
                    if (t >= W + 1)
                        rowN[t] = sup[(size_t)((W + 1) * 64 + lane) * 16 + t];
            }
            // intra-word greedy: 64-step cndmask chain, reads batched 16 at
            // a time (reads are chain-independent -> one lgkm wait per batch)
#pragma unroll
            for (int g = 0; g < 4; ++g) {
                u64 rb[16];
#pragma unroll
                for (int t = 0; t < 16; ++t) rb[t] = bc[g * 16 + t];
#pragma unroll
                for (int t = 0; t < 16; ++t) {
                    int bb = g * 16 + t;
                    bool kb = (kwW >> bb) & 1ULL;
                    kwW &= kb ? ~rb[t] : ~0ULL;
                }
            }
            if (lane == 0) ksh[W] = kwW;
            bool me = (kwW >> lane) & 1ULL;
#pragma unroll
            for (int t = W + 1; t < 16; ++t) acc[t] |= me ? row[t] : 0ULL;
#pragma unroll
            for (int t = 0; t < 16; ++t) row[t] = rowN[t];
        }
    }
    __syncthreads();

    // ---- phase 2: scan + eval ----
    {
        int i = b + (wv << 8);
        float4 A = circ_p[i];
        for (int jb = 0; jb < 1024; jb += 64) {
            int j = jb + lane;
            int r = rankinv[j];
            bool q = (ksh[r >> 6] >> (r & 63)) & 1ULL;  // sampled[j]
            if (q) {
                float4 B = circ_g[j];
                float dx = A.x - B.x, dy = A.y - B.y;
                float lim = A.z + B.z + 1e-3f;
                q = (dx * dx + dy * dy) <= lim * lim;
            }
            if (q) {
                unsigned pos = atomicAdd(&cnt_s, 1u);
                ring[pos] = (unsigned)((i << 10) | j);
            }
        }
    }
    __syncthreads();
    {
        unsigned n = cnt_s;
        for (unsigned t = tid; t < n; t += 256) {
            unsigned p = ring[t];
            int i = (p >> 10) & 1023, j = p & 1023;
            float Ax = pred[i * 7 + 0], Ay = pred[i * 7 + 1], Az = pred[i * 7 + 2];
            float Adx = pred[i * 7 + 3], Ady = pred[i * 7 + 4], Adz = pred[i * 7 + 5];
            float Ar = pred[i * 7 + 6];
            float Bx = gt[j * 8 + 0], By = gt[j * 8 + 1], Bz = gt[j * 8 + 2];
            float Bdx = gt[j * 8 + 3], Bdy = gt[j * 8 + 4], Bdz = gt[j * 8 + 5];
            float Br = gt[j * 8 + 6];
            float inter = rect_inter_area(Ax, Ay, Adx, Ady, Ar,
                                          Bx, By, Bdx, Bdy, Br);
            float amax = Az + Adz * 0.5f, amin = Az - Adz * 0.5f;
            float bmax = Bz + Bdz * 0.5f, bmin = Bz - Bdz * 0.5f;
            float oh = fmaxf(fminf(amax, bmax) - fmaxf(amin, bmin), 0.0f);
            float inter3d = inter * oh;
            float va = Adx * Ady * Adz, vb = Bdx * Bdy * Bdz;
            float iou = inter3d / fmaxf(va + vb - inter3d, 1e-8f);
            u64 pk = (((u64)__float_as_uint(iou)) << 32) | (u64)(1023 - j);
            int r = (i - b) >> 8;
            atomicMax(&rm[r], pk);
        }
    }
    __syncthreads();
    if (tid < 4) {
        int i = b + (tid << 8);
        u64 v = rm[tid];
        float fv = __uint_as_float((unsigned)(v >> 32));
        int j = 1023 - (int)(v & 0xFFFFFFFFULL);
        float mo = (fv > 0.75f) ? 1.0f : ((fv < 0.25f) ? 0.0f : fv);
        out[2 * NB + i] = mo;
        out[3 * NB + i] = (float)j;
    }
}

// ---------------------------------------------------------------------------
// Workspace layout:
//   [0,       4096)    int   rankinv[1024]
//   [4096,    36864)   float sbox[1024*8]
//   [40960,   172032)  u64   sup[1024*16]
//   [172032,  188416)  float4 circ_s[1024]
//   [188416,  204800)  float4 circ_g[1024]
//   [204800,  221184)  float4 circ_p[1024]
// ---------------------------------------------------------------------------
extern "C" void kernel_launch(void* const* d_in, const int* in_sizes, int n_in,
                              void* d_out, int out_size, void* d_ws, size_t ws_size,
                              hipStream_t stream) {
    const float* labels = (const float*)d_in[0];
    const float* pred   = (const float*)d_in[1];
    const float* gt     = (const float*)d_in[2];
    const float* cls    = (const float*)d_in[3];
    float* out = (float*)d_out;

    char* ws = (char*)d_ws;
    int* rankinv   = (int*)ws;
    float* sbox    = (float*)(ws + 4096);
    u64* sup       = (u64*)(ws + 40960);
    float4* circ_s = (float4*)(ws + 172032);
    float4* circ_g = (float4*)(ws + 188416);
    float4* circ_p = (float4*)(ws + 204800);

    prep_sa_kernel<<<256, 256, 0, stream>>>(labels, pred, gt, cls, out,
                                            rankinv, sbox, circ_s, circ_g,
                                            circ_p);
    supA_sa_kernel<<<256, 256, 0, stream>>>(sbox, circ_s, sup);
    outB_fused_kernel<<<256, 256, 0, stream>>>(pred, gt, rankinv, circ_p,
                                               circ_g, sup, out);
}